// Round 1
// 311.449 us; speedup vs baseline: 1.0741x; 1.0741x over previous
//
#include <hip/hip_runtime.h>
#include <hip/hip_bf16.h>
#include <stdint.h>

// Problem constants (from reference)
#define N_NODES 100000
#define N_EDGES 1600000
#define NFEAT   256
#define NHID    128
#define NEG_SLOPE 0.2f

#define NB_B       1563       // buckets of 64 nodes: ceil(100000/64)
#define SLAB       2048       // fixed slab per bucket (mean fill 1024)
#define BIN_BLOCKS 512        // 2 blocks/CU; per-(block,bucket) run ~2 edges

typedef __attribute__((ext_vector_type(8))) short short8;   // 8 bf16 (4 VGPRs)
typedef __attribute__((ext_vector_type(4))) float f32x4;    // MFMA C/D frag

__device__ __forceinline__ int clamp_node(int v) {
    unsigned u = (unsigned)v;
    return (u < (unsigned)N_NODES) ? (int)u : 0;
}

// fp32 -> bf16 (RNE). Exact when the fp32 value is already bf16-rounded.
__device__ __forceinline__ unsigned short f2bf(float f) {
    unsigned u = __float_as_uint(f);
    return (unsigned short)((u + 0x7fffu + ((u >> 16) & 1u)) >> 16);
}
// packed pair -> v_cvt_pk_bf16_f32 (low = a, high = b)
__device__ __forceinline__ unsigned pkbf(float a, float b) {
    __hip_bfloat162 t = __float22bfloat162_rn(make_float2(a, b));
    return *reinterpret_cast<unsigned*>(&t);
}
__device__ __forceinline__ float bflo(unsigned p) { return __uint_as_float(p << 16); }
__device__ __forceinline__ float bfhi(unsigned p) { return __uint_as_float(p & 0xffff0000u); }

// ---------------------------------------------------------------------------
// K0: W [256,128] fp32 -> Wt [128,256] bf16 (n-major).
// ---------------------------------------------------------------------------
__global__ __launch_bounds__(256) void k_conv(
    const float* __restrict__ W, unsigned short* __restrict__ Wt)
{
    int id = blockIdx.x * 256 + threadIdx.x;  // n*256 + k
    int n = id >> 8, k = id & 255;
    Wt[id] = f2bf(W[k * NHID + n]);
}

// ---------------------------------------------------------------------------
// K1: h = x @ W via bf16 MFMA (fp32 accum) -> hb bf16, fused attention
// scalars. SOFTWARE-PIPELINED K-loop: tile kt+1's global loads are issued
// right after the RAW barrier, so they overlap ds_read+MFMA of tile kt and
// drain at the next iteration's LDS store.
// ---------------------------------------------------------------------------
#define LDS_STRIDE 40
__global__ __launch_bounds__(256) void k_gemm_mfma(
    const float* __restrict__ x,            // [N, 256] fp32 (bf16-valued)
    const unsigned short* __restrict__ Wt,  // [128, 256] bf16, n-major
    const float* __restrict__ atts,
    const float* __restrict__ attd,
    unsigned short* __restrict__ hb,        // [N, 128] bf16
    float* __restrict__ asrc,
    float* __restrict__ adst)
{
    __shared__ unsigned short As[128 * LDS_STRIDE];
    __shared__ unsigned short Bs[128 * LDS_STRIDE];
    __shared__ float satt[128][2];

    const int tid  = threadIdx.x;
    const int wave = tid >> 6;
    const int lane = tid & 63;
    const int wm = wave >> 1, wn = wave & 1;
    const int lr = lane & 15, q = lane >> 4;
    const int blockM = blockIdx.x * 128;

    const int sr = tid >> 1;
    const int hh = tid & 1;

    if (tid < 128) { satt[tid][0] = 0.f; satt[tid][1] = 0.f; }

    f32x4 acc[4][4];
#pragma unroll
    for (int a = 0; a < 4; ++a)
#pragma unroll
        for (int b = 0; b < 4; ++b) acc[a][b] = 0.f;

    const int growA = min(blockM + sr, N_NODES - 1);
    const float* xrow = x + (size_t)growA * NFEAT + hh * 16;
    const unsigned short* wrow = Wt + sr * NFEAT + hh * 16;

    float4 va0, va1, va2, va3;
    uint4  vb0, vb1;
    {   // preload tile 0
        const float4* xp = (const float4*)xrow;
        va0 = xp[0]; va1 = xp[1]; va2 = xp[2]; va3 = xp[3];
        vb0 = *(const uint4*)(wrow);
        vb1 = *(const uint4*)(wrow + 8);
    }

    for (int kt = 0; kt < 8; ++kt) {
        __syncthreads();  // WAR: previous iter's frag reads done
        uint4 pa0 = make_uint4(pkbf(va0.x, va0.y), pkbf(va0.z, va0.w),
                               pkbf(va1.x, va1.y), pkbf(va1.z, va1.w));
        uint4 pa1 = make_uint4(pkbf(va2.x, va2.y), pkbf(va2.z, va2.w),
                               pkbf(va3.x, va3.y), pkbf(va3.z, va3.w));
        *(uint4*)&As[sr * LDS_STRIDE + hh * 16 + 0] = pa0;
        *(uint4*)&As[sr * LDS_STRIDE + hh * 16 + 8] = pa1;
        *(uint4*)&Bs[sr * LDS_STRIDE + hh * 16 + 0] = vb0;
        *(uint4*)&Bs[sr * LDS_STRIDE + hh * 16 + 8] = vb1;
        __syncthreads();  // RAW: writes visible

        if (kt < 7) {     // issue next tile's loads NOW (overlap MFMA)
            const float4* xp = (const float4*)(xrow + (kt + 1) * 32);
            va0 = xp[0]; va1 = xp[1]; va2 = xp[2]; va3 = xp[3];
            vb0 = *(const uint4*)(wrow + (kt + 1) * 32);
            vb1 = *(const uint4*)(wrow + (kt + 1) * 32 + 8);
        }

        short8 af[4], bfr[4];
#pragma unroll
        for (int mt = 0; mt < 4; ++mt)
            af[mt] = *(const short8*)&As[(wm * 64 + mt * 16 + lr) * LDS_STRIDE + q * 8];
#pragma unroll
        for (int nt = 0; nt < 4; ++nt)
            bfr[nt] = *(const short8*)&Bs[(wn * 64 + nt * 16 + lr) * LDS_STRIDE + q * 8];

#pragma unroll
        for (int mt = 0; mt < 4; ++mt)
#pragma unroll
            for (int nt = 0; nt < 4; ++nt)
                acc[mt][nt] = __builtin_amdgcn_mfma_f32_16x16x32_bf16(
                    af[mt], bfr[nt], acc[mt][nt], 0, 0, 0);
    }

    // ---- fused attention partials: per-row dot with atts/attd ----
    float attsv[4], attdv[4];
#pragma unroll
    for (int nt = 0; nt < 4; ++nt) {
        attsv[nt] = atts[wn * 64 + nt * 16 + lr];
        attdv[nt] = attd[wn * 64 + nt * 16 + lr];
    }
#pragma unroll
    for (int mt = 0; mt < 4; ++mt) {
#pragma unroll
        for (int reg = 0; reg < 4; ++reg) {
            float s = 0.f, d = 0.f;
#pragma unroll
            for (int nt = 0; nt < 4; ++nt) {
                float v = acc[mt][nt][reg];
                s += v * attsv[nt];
                d += v * attdv[nt];
            }
#pragma unroll
            for (int mask = 8; mask > 0; mask >>= 1) {
                s += __shfl_xor(s, mask);
                d += __shfl_xor(d, mask);
            }
            if (lr == 0) {
                int lrow = wm * 64 + mt * 16 + q * 4 + reg;
                atomicAdd(&satt[lrow][0], s);
                atomicAdd(&satt[lrow][1], d);
            }
        }
    }

    // ---- hb epilogue ----
#pragma unroll
    for (int mt = 0; mt < 4; ++mt) {
#pragma unroll
        for (int reg = 0; reg < 4; ++reg) {
            int grow = blockM + wm * 64 + mt * 16 + q * 4 + reg;
            if (grow < N_NODES) {
                unsigned short* hp = hb + (size_t)grow * NHID + wn * 64 + lr;
#pragma unroll
                for (int nt = 0; nt < 4; ++nt)
                    hp[nt * 16] = f2bf(acc[mt][nt][reg]);
            }
        }
    }

    __syncthreads();
    if (tid < 128) {
        int g = blockM + tid;
        if (g < N_NODES) {
            asrc[g] = satt[tid][0];
            adst[g] = satt[tid][1];
        }
    }
}

// ---------------------------------------------------------------------------
// K2: bin edges into fixed per-bucket slabs (bucket = dst>>6, slab = 2048).
// 512 blocks (2/CU). Per-block LDS histogram -> one global cursor bump per
// (block,bucket) -> LDS-cursor scatter. Payload = src | (dst&63)<<17.
// ---------------------------------------------------------------------------
__global__ __launch_bounds__(256) void k_bin(
    const int* __restrict__ ei, int* __restrict__ gcur,
    unsigned* __restrict__ staged)
{
    __shared__ int hist[NB_B];   // then reused as cursor
    __shared__ int base[NB_B];
    const int t = threadIdx.x;
    const int per = (N_EDGES + BIN_BLOCKS - 1) / BIN_BLOCKS;  // 3125
    const int e0 = blockIdx.x * per;
    const int e1 = min(e0 + per, N_EDGES);

    for (int i = t; i < NB_B; i += 256) hist[i] = 0;
    __syncthreads();
    for (int e = e0 + t; e < e1; e += 256)
        atomicAdd(&hist[clamp_node(ei[N_EDGES + e]) >> 6], 1);
    __syncthreads();
    for (int i = t; i < NB_B; i += 256) {
        int c = hist[i];
        base[i] = c ? atomicAdd(&gcur[i], c) : 0;
        hist[i] = 0;  // becomes cursor
    }
    __syncthreads();
    for (int e = e0 + t; e < e1; e += 256) {
        int d = clamp_node(ei[N_EDGES + e]);
        int s = clamp_node(ei[e]);
        int b = d >> 6;
        int pos = base[b] + atomicAdd(&hist[b], 1);
        if (pos < SLAB)  // Poisson(1024) vs 2048: overflow prob ~0
            staged[(size_t)b * SLAB + pos] = (unsigned)s | ((unsigned)(d & 63) << 17);
    }
}

// ---------------------------------------------------------------------------
// K3 (fused, was k_bsort + k_agg): per-bucket counting sort stays IN LDS
// (no meta round trip to HBM, one fewer dispatch), then per-node
// aggregation + fused FC + log_softmax. 4 waves/block; wave w owns local
// nodes [w*16, w*16+16). Meta comes from LDS broadcast reads (~120 cyc)
// instead of global (~200-400 cyc); gather addressing is 32-bit.
// ---------------------------------------------------------------------------
__global__ __launch_bounds__(256) void k_sort_agg(
    const unsigned* __restrict__ staged, const int* __restrict__ gcur,
    const float* __restrict__ asrc, const float* __restrict__ adst,
    const unsigned short* __restrict__ hb,
    const float* __restrict__ bias, const float* __restrict__ fcw,
    const float* __restrict__ fcb, float* __restrict__ out)
{
    __shared__ float2 buf[SLAB];        // 16 KB sorted (src, ew)
    __shared__ int hist[64], scanv[64], cntv[64];
    __shared__ float asrc_s[64], adst_s[64];

    const int b = blockIdx.x;
    const int t = threadIdx.x;
    const int eb = b * SLAB;
    const int n = min(gcur[b], SLAB);
    const int nodeStart = b * 64;

    if (t < 64) {
        hist[t] = 0;
        int gi = nodeStart + t;
        adst_s[t] = (gi < N_NODES) ? adst[gi] : 0.f;
        asrc_s[t] = (gi < N_NODES) ? asrc[gi] : 0.f;
    }
    __syncthreads();

    for (int j = t; j < n; j += 256)
        atomicAdd(&hist[(staged[eb + j] >> 17) & 63], 1);
    __syncthreads();

    if (t < 64) {  // wave-parallel exclusive scan (first wave, lanes 0..63)
        int v = hist[t];
        int sc = v;
#pragma unroll
        for (int off = 1; off < 64; off <<= 1) {
            int u = __shfl_up(sc, off);
            if (t >= off) sc += u;
        }
        scanv[t] = sc - v;
        cntv[t] = v;
        hist[t] = 0;  // becomes cursor
    }
    __syncthreads();

    for (int j = t; j < n; j += 256) {
        unsigned pk = staged[eb + j];
        int s  = pk & 0x1FFFF;
        int dl = (pk >> 17) & 63;
        float a = asrc[s] + adst_s[dl];
        a = (a > 0.f) ? a : NEG_SLOPE * a;
        float ew = __expf(fminf(a, 60.f));
        int pos = scanv[dl] + atomicAdd(&hist[dl], 1);
        buf[pos] = make_float2(__int_as_float(s), ew);
    }
    __syncthreads();

    // ---- aggregation + fused FC + log_softmax ----
    const int wave = t >> 6;
    const int lane = t & 63;
    const unsigned* hrows = (const unsigned*)hb;

    // hoist per-lane FC constants out of the node loop
    const float b0 = bias[2 * lane], b1 = bias[2 * lane + 1];
    const float w00 = fcw[2 * lane], w01 = fcw[2 * lane + 1];
    const float w10 = fcw[NHID + 2 * lane], w11 = fcw[NHID + 2 * lane + 1];
    const float fb0 = fcb[0], fb1 = fcb[1];

    for (int ln = wave * 16; ln < wave * 16 + 16; ++ln) {
        int i = nodeStart + ln;
        if (i >= N_NODES) break;  // only in the last block (wave-uniform)

        // self loop
        float e0 = asrc_s[ln] + adst_s[ln];
        e0 = (e0 > 0.f) ? e0 : NEG_SLOPE * e0;
        float w = __expf(fminf(e0, 60.f));
        unsigned pself = hrows[(unsigned)i * 64u + lane];
        float accx = w * bflo(pself), accy = w * bfhi(pself), ssum = w;

        const int jb = scanv[ln];
        const int nn = cntv[ln];
        int j = 0;
        for (; j + 8 <= nn; j += 8) {
            float2 m[8];
            unsigned p[8];
#pragma unroll
            for (int u = 0; u < 8; ++u) m[u] = buf[jb + j + u];
#pragma unroll
            for (int u = 0; u < 8; ++u)
                p[u] = hrows[(unsigned)__float_as_int(m[u].x) * 64u + lane];
#pragma unroll
            for (int u = 0; u < 8; ++u) {
                accx += m[u].y * bflo(p[u]);
                accy += m[u].y * bfhi(p[u]);
                ssum += m[u].y;
            }
        }
        for (; j < nn; ++j) {
            float2 m = buf[jb + j];
            unsigned p = hrows[(unsigned)__float_as_int(m.x) * 64u + lane];
            accx += m.y * bflo(p);
            accy += m.y * bfhi(p);
            ssum += m.y;
        }

        float inv = 1.0f / (ssum + 1e-16f);
        float ox = accx * inv + b0;
        float oy = accy * inv + b1;

        float l0 = ox * w00 + oy * w01;
        float l1 = ox * w10 + oy * w11;
#pragma unroll
        for (int off = 32; off > 0; off >>= 1) {
            l0 += __shfl_down(l0, off);
            l1 += __shfl_down(l1, off);
        }
        if (lane == 0) {
            l0 += fb0;
            l1 += fb1;
            float m = fmaxf(l0, l1);
            float ls = m + __logf(__expf(l0 - m) + __expf(l1 - m));
            ((float2*)out)[i] = make_float2(l0 - ls, l1 - ls);
        }
    }
}

// ---------------------------------------------------------------------------
extern "C" void kernel_launch(void* const* d_in, const int* in_sizes, int n_in,
                              void* d_out, int out_size, void* d_ws, size_t ws_size,
                              hipStream_t stream)
{
    const float* x    = (const float*)d_in[0];
    const int*   ei   = (const int*)d_in[1];
    const float* W    = (const float*)d_in[2];
    const float* atts = (const float*)d_in[3];
    const float* attd = (const float*)d_in[4];
    const float* bias = (const float*)d_in[5];
    const float* fcw  = (const float*)d_in[6];
    const float* fcb  = (const float*)d_in[7];
    float*       out  = (float*)d_out;

    char* base = (char*)d_ws;
    size_t off = 0;
    auto carve = [&](size_t bytes) -> char* {
        char* p = base + off;
        off = (off + bytes + 255) & ~(size_t)255;
        return p;
    };
    unsigned short* hb     = (unsigned short*)carve((size_t)N_NODES * NHID * 2); // 25.6 MB
    float*          asrc   = (float*)carve(N_NODES * 4);
    float*          adst   = (float*)carve(N_NODES * 4);
    int*            gcur   = (int*)carve(NB_B * 4);
    unsigned*       staged = (unsigned*)carve((size_t)NB_B * SLAB * 4);          // 12.8 MB
    unsigned short* Wt     = (unsigned short*)carve(NHID * NFEAT * 2);           // 64 KB
    (void)ws_size; (void)in_sizes; (void)n_in; (void)out_size;

    hipMemsetAsync(gcur, 0, NB_B * 4, stream);

    const int GB = (N_NODES + 127) / 128;  // 782

    k_conv<<<(NHID * NFEAT) / 256, 256, 0, stream>>>(W, Wt);
    k_gemm_mfma<<<GB, 256, 0, stream>>>(x, Wt, atts, attd, hb, asrc, adst);
    k_bin<<<BIN_BLOCKS, 256, 0, stream>>>(ei, gcur, staged);
    k_sort_agg<<<NB_B, 256, 0, stream>>>(staged, gcur, asrc, adst, hb,
                                         bias, fcw, fcb, out);
}